// Round 1
// baseline (205.115 us; speedup 1.0000x reference)
//
#include <hip/hip_runtime.h>

// Correlation layer: out[b,o,h,w] = mean_c x1[b,c,h,w] * x2[b,c,h+dh,w+dw]
// B=8 C=128 H=W=128, d=4 -> 81 offsets (o = (dh+4)*9 + (dw+4)).
//
// Design (R1):
//  - dh split into 3 groups of 3 (grid dim) -> 27 accum offsets/thread-pass
//  - 4 consecutive pixels per thread (w0 % 4 == 0) -> window = 12 floats =
//    3 aligned float4 LDS reads shared by 4 pixels, 108 FMA per channel
//  - channel split x2 inside the WG (threads 0-127: c 0..63, 128-255: c 64..127),
//    cross-half reduction through LDS at the end
//  - WG 256 thr = 2 halves x (4 rows x 32 w-chunks); grid = 8b x 32 htiles x 3 groups
//    = 768 WGs x 4 waves = 3072 waves = 3/SIMD at <=170 VGPR (launch_bounds 256,3)

constexpr int Bn = 8, Cn = 128, Hn = 128, Wn = 128;
constexpr int HWn = Hn * Wn;
constexpr int TH = 4;            // output rows per tile
constexpr int NDH = 3;           // dh values per group
constexpr int NR = TH + NDH - 1; // staged x2 rows = 6
constexpr int WP = 144;          // padded LDS row: cols -4..135 at idx 0..139
constexpr int NF4 = (NR * 140) / 4; // 210 float4 staging slots

__global__ __launch_bounds__(256, 3)
void corr_kernel(const float* __restrict__ x1, const float* __restrict__ x2,
                 float* __restrict__ out) {
  __shared__ float s2[2][NR][WP];     // per-half x2 tile (one channel)
  __shared__ float sred[128][36];     // cross-half reduction buffer

  const int t    = threadIdx.x;
  const int half = t >> 7;            // 0: c 0..63, 1: c 64..127
  const int q    = t & 127;
  const int row  = q >> 5;            // 0..3 (output row within tile)
  const int w0   = (q & 31) << 2;     // 0,4,...,124

  const int bx   = blockIdx.x;
  const int g    = bx % 3;            // dh group
  const int tile = bx / 3;
  const int b    = tile >> 5;
  const int h0   = (tile & 31) * TH;
  const int dhm  = g * NDH - 4;       // first dh of group: -4, -1, +2

  // --- precompute the (up to 2) staging slots this thread fills each channel ---
  const int i0 = q, i1 = q + 128;
  const int sr0 = i0 / 35, fc0 = i0 % 35;
  int sr1 = i1 / 35; const int fc1 = i1 % 35;
  const bool act1 = (i1 < NF4);
  if (sr1 > NR - 1) sr1 = NR - 1;     // clamp; store gated by act1
  const int gr0 = h0 + dhm + sr0;
  const int gr1 = h0 + dhm + sr1;
  const bool ok0 = ((unsigned)gr0 < (unsigned)Hn) && (fc0 >= 1) && (fc0 <= 32);
  const bool ok1 = act1 && ((unsigned)gr1 < (unsigned)Hn) && (fc1 >= 1) && (fc1 <= 32);
  const int off0 = gr0 * Wn + fc0 * 4 - 4;  // cols fc*4-4 .. fc*4-1
  const int off1 = gr1 * Wn + fc1 * 4 - 4;
  float* lp0 = &s2[half][sr0][fc0 * 4];
  float* lp1 = &s2[half][sr1][fc1 * 4];

  const float* x1c = x1 + (size_t)b * Cn * HWn + (size_t)(half * 64) * HWn
                        + (h0 + row) * Wn + w0;
  const float* x2c = x2 + (size_t)b * Cn * HWn + (size_t)(half * 64) * HWn;

  float4 acc[NDH][9];
#pragma unroll
  for (int r = 0; r < NDH; ++r)
#pragma unroll
    for (int dw = 0; dw < 9; ++dw) acc[r][dw] = make_float4(0.f, 0.f, 0.f, 0.f);

#pragma unroll 1
  for (int cc = 0; cc < 64; ++cc) {
    // x1 for this thread's 4 pixels (independent of LDS)
    const float4 a = *(const float4*)x1c;
    // stage x2 rows [h0+dhm, h0+dhm+5], cols -4..135 (zero-filled halo)
    float4 v0 = make_float4(0.f, 0.f, 0.f, 0.f);
    float4 v1 = make_float4(0.f, 0.f, 0.f, 0.f);
    if (ok0) v0 = *(const float4*)(x2c + off0);
    if (ok1) v1 = *(const float4*)(x2c + off1);
    *(float4*)lp0 = v0;
    if (act1) *(float4*)lp1 = v1;
    __syncthreads();

#pragma unroll
    for (int r = 0; r < NDH; ++r) {
      const float* srow = &s2[half][row + r][w0];  // idx w0 == col w0-4
      const float4 wa = *(const float4*)(srow);
      const float4 wb = *(const float4*)(srow + 4);
      const float4 wc = *(const float4*)(srow + 8);
      const float win[12] = {wa.x, wa.y, wa.z, wa.w, wb.x, wb.y, wb.z, wb.w,
                             wc.x, wc.y, wc.z, wc.w};
      // pixel j (j=0..3) with offset dw-4 reads win[j+dw]
#pragma unroll
      for (int dw = 0; dw < 9; ++dw) {
        acc[r][dw].x += a.x * win[dw + 0];
        acc[r][dw].y += a.y * win[dw + 1];
        acc[r][dw].z += a.z * win[dw + 2];
        acc[r][dw].w += a.w * win[dw + 3];
      }
    }
    x1c += HWn;
    x2c += HWn;
    __syncthreads();
  }

  // --- cross-half reduction + store ---
  const float scale = 1.0f / 128.0f;
  float* ob = out + (size_t)b * 81 * HWn + (size_t)(h0 + row) * Wn + w0;
#pragma unroll
  for (int r = 0; r < NDH; ++r) {
    if (half) {
#pragma unroll
      for (int dw = 0; dw < 9; ++dw) *(float4*)&sred[q][dw * 4] = acc[r][dw];
    }
    __syncthreads();
    if (!half) {
      const int obase = (g * 3 + r) * 9;
#pragma unroll
      for (int dw = 0; dw < 9; ++dw) {
        const float4 s = *(const float4*)&sred[q][dw * 4];
        const float4 m = acc[r][dw];
        float4 rz;
        rz.x = (m.x + s.x) * scale;
        rz.y = (m.y + s.y) * scale;
        rz.z = (m.z + s.z) * scale;
        rz.w = (m.w + s.w) * scale;
        *(float4*)(ob + (size_t)(obase + dw) * HWn) = rz;
      }
    }
    __syncthreads();
  }
}

extern "C" void kernel_launch(void* const* d_in, const int* in_sizes, int n_in,
                              void* d_out, int out_size, void* d_ws, size_t ws_size,
                              hipStream_t stream) {
  const float* x1 = (const float*)d_in[0];
  const float* x2 = (const float*)d_in[1];
  float* out = (float*)d_out;
  const int n_wgs = Bn * (Hn / TH) * 3;  // 768
  corr_kernel<<<dim3(n_wgs), dim3(256), 0, stream>>>(x1, x2, out);
}

// Round 2
// 189.088 us; speedup vs baseline: 1.0848x; 1.0848x over previous
//
#include <hip/hip_runtime.h>

// Correlation layer: out[b,o,h,w] = mean_c x1[b,c,h,w] * x2[b,c,h+dh,w+dw]
// B=8 C=128 H=W=128, d=4 -> 81 offsets (o = (dh+4)*9 + (dw+4)).
//
// R2 changes vs R1 (101 us, VALUBusy 27%, ~1100 cyc/iter barrier+load stall):
//  - double-buffered LDS staging + register prefetch -> ONE barrier per
//    channel iteration; x2/x1 global latency hidden behind previous compute
//  - XCD swizzle: assuming round-robin blockIdx->XCD, XCD k owns batch k, so
//    a tile's 3 dh-groups (same x1 reads) share one XCD L2 -> x1 rereads hit L2

constexpr int Bn = 8, Cn = 128, Hn = 128, Wn = 128;
constexpr int HWn = Hn * Wn;
constexpr int TH = 4;            // output rows per tile
constexpr int NDH = 3;           // dh values per group
constexpr int NR = TH + NDH - 1; // staged x2 rows = 6
constexpr int WP = 144;          // padded LDS row: cols -4..135 at idx 0..139
constexpr int NF4 = (NR * 140) / 4; // 210 float4 staging slots

__global__ __launch_bounds__(256, 3)
void corr_kernel(const float* __restrict__ x1, const float* __restrict__ x2,
                 float* __restrict__ out) {
  __shared__ float s2[2][2][NR][WP];  // [buf][half][row][col]
  __shared__ float sred[128][36];     // cross-half reduction buffer

  const int t    = threadIdx.x;
  const int half = t >> 7;            // 0: c 0..63, 1: c 64..127
  const int q    = t & 127;
  const int row  = q >> 5;            // 0..3 (output row within tile)
  const int w0   = (q & 31) << 2;     // 0,4,...,124

  // --- XCD swizzle: tile's 3 groups + 32 tiles of one batch per XCD ---
  const int phys = blockIdx.x;        // 0..767
  const int xcd  = phys & 7;          // assumed round-robin placement
  const int slot = phys >> 3;         // 0..95
  const int tl   = slot / 3;          // 0..31
  const int g    = slot % 3;          // dh group
  const int tile = xcd * 32 + tl;     // b = tile>>5 == xcd
  const int b    = tile >> 5;
  const int h0   = (tile & 31) * TH;
  const int dhm  = g * NDH - 4;       // first dh of group: -4, -1, +2

  // --- staging slots this thread fills each channel ---
  const int i0 = q, i1 = q + 128;
  const int sr0 = i0 / 35, fc0 = i0 % 35;
  int sr1 = i1 / 35; const int fc1 = i1 % 35;
  const bool act1 = (i1 < NF4);
  if (sr1 > NR - 1) sr1 = NR - 1;     // clamp; store gated by act1
  const int gr0 = h0 + dhm + sr0;
  const int gr1 = h0 + dhm + sr1;
  const bool ok0 = ((unsigned)gr0 < (unsigned)Hn) && (fc0 >= 1) && (fc0 <= 32);
  const bool ok1 = act1 && ((unsigned)gr1 < (unsigned)Hn) && (fc1 >= 1) && (fc1 <= 32);
  const int off0 = gr0 * Wn + fc0 * 4 - 4;  // cols fc*4-4 .. fc*4-1
  const int off1 = gr1 * Wn + fc1 * 4 - 4;

  const float* x1c = x1 + (size_t)b * Cn * HWn + (size_t)(half * 64) * HWn
                        + (h0 + row) * Wn + w0;
  const float* x2c = x2 + (size_t)b * Cn * HWn + (size_t)(half * 64) * HWn;

  float4 acc[NDH][9];
#pragma unroll
  for (int r = 0; r < NDH; ++r)
#pragma unroll
    for (int dw = 0; dw < 9; ++dw) acc[r][dw] = make_float4(0.f, 0.f, 0.f, 0.f);

  // --- prologue: prefetch channel 0 into registers ---
  float4 pv0 = make_float4(0.f, 0.f, 0.f, 0.f);
  float4 pv1 = make_float4(0.f, 0.f, 0.f, 0.f);
  if (ok0) pv0 = *(const float4*)(x2c + off0);
  if (ok1) pv1 = *(const float4*)(x2c + off1);
  float4 pa = *(const float4*)x1c;

#pragma unroll 1
  for (int cc = 0; cc < 64; ++cc) {
    const int buf = cc & 1;
    // write staged channel cc (prefetched last iter; vmcnt long satisfied)
    *(float4*)&s2[buf][half][sr0][fc0 * 4] = pv0;
    if (act1) *(float4*)&s2[buf][half][sr1][fc1 * 4] = pv1;
    const float4 a = pa;
    // issue prefetch for channel cc+1 (lands during this iter's compute)
    if (cc < 63) {
      const float* nx2 = x2c + (size_t)(cc + 1) * HWn;
      if (ok0) pv0 = *(const float4*)(nx2 + off0);
      if (ok1) pv1 = *(const float4*)(nx2 + off1);
      pa = *(const float4*)(x1c + (size_t)(cc + 1) * HWn);
    }
    __syncthreads();  // buf[cc&1] visible; also separates last iter's reads
                      // of buf[(cc+1)&1] from next iter's writes to it

#pragma unroll
    for (int r = 0; r < NDH; ++r) {
      const float* srow = &s2[buf][half][row + r][w0];  // idx w0 == col w0-4
      const float4 wa = *(const float4*)(srow);
      const float4 wb = *(const float4*)(srow + 4);
      const float4 wc = *(const float4*)(srow + 8);
      const float win[12] = {wa.x, wa.y, wa.z, wa.w, wb.x, wb.y, wb.z, wb.w,
                             wc.x, wc.y, wc.z, wc.w};
      // pixel j (j=0..3) with offset dw-4 reads win[j+dw]
#pragma unroll
      for (int dw = 0; dw < 9; ++dw) {
        acc[r][dw].x += a.x * win[dw + 0];
        acc[r][dw].y += a.y * win[dw + 1];
        acc[r][dw].z += a.z * win[dw + 2];
        acc[r][dw].w += a.w * win[dw + 3];
      }
    }
  }

  // --- cross-half reduction + store ---
  const float scale = 1.0f / 128.0f;
  float* ob = out + (size_t)b * 81 * HWn + (size_t)(h0 + row) * Wn + w0;
#pragma unroll
  for (int r = 0; r < NDH; ++r) {
    if (half) {
#pragma unroll
      for (int dw = 0; dw < 9; ++dw) *(float4*)&sred[q][dw * 4] = acc[r][dw];
    }
    __syncthreads();
    if (!half) {
      const int obase = (g * 3 + r) * 9;
#pragma unroll
      for (int dw = 0; dw < 9; ++dw) {
        const float4 s = *(const float4*)&sred[q][dw * 4];
        const float4 m = acc[r][dw];
        float4 rz;
        rz.x = (m.x + s.x) * scale;
        rz.y = (m.y + s.y) * scale;
        rz.z = (m.z + s.z) * scale;
        rz.w = (m.w + s.w) * scale;
        *(float4*)(ob + (size_t)(obase + dw) * HWn) = rz;
      }
    }
    __syncthreads();
  }
}

extern "C" void kernel_launch(void* const* d_in, const int* in_sizes, int n_in,
                              void* d_out, int out_size, void* d_ws, size_t ws_size,
                              hipStream_t stream) {
  const float* x1 = (const float*)d_in[0];
  const float* x2 = (const float*)d_in[1];
  float* out = (float*)d_out;
  const int n_wgs = Bn * (Hn / TH) * 3;  // 768 = 3 per CU
  corr_kernel<<<dim3(n_wgs), dim3(256), 0, stream>>>(x1, x2, out);
}